// Round 4
// baseline (195.024 us; speedup 1.0000x reference)
//
#include <hip/hip_runtime.h>

#define NTILES_X 65          // ceil(1026/16)
#define NTILES   (65*65)     // 4225
#define OHW      1026
#define NCHUNK   32

typedef unsigned int  uint;
typedef unsigned short ushort;
typedef float  floatx16 __attribute__((ext_vector_type(16)));
typedef __bf16 bf16x8   __attribute__((ext_vector_type(8)));

__device__ __forceinline__ uint pk2(float a, float b) {
    ushort lo = __builtin_bit_cast(ushort, (__bf16)a);
    ushort hi = __builtin_bit_cast(ushort, (__bf16)b);
    return (uint)lo | ((uint)hi << 16);
}

// ---------------------------------------------------------------------------
// Kernel 1: fused conv1 (3->32, k3, pad2, fp32 VALU) + MFMA bf16 gram
// F stored as bf16 [px][32ch], 8B-slot-swizzled: slot(oc4) at (oc4 ^ (px&7)).
// ---------------------------------------------------------------------------
__global__ __launch_bounds__(256, 6) void k_conv_gram(
    const float* __restrict__ x,   // [3][1024][1024]
    const float* __restrict__ w1,  // [32][3][3][3]
    const float* __restrict__ b1,  // [32]
    float* __restrict__ partial,   // [nblk][1024]
    int nblk)
{
    __shared__ float  sIn[3*18*18];    // 3.9 KB input tile + halo
    __shared__ ushort sFb[256*32];     // 16 KB bf16 F[px][ch]; aliased for reduce

    const int t    = threadIdx.x;
    const int wv   = t >> 6;
    const int lane = t & 63;
    const int h    = lane >> 5;       // half-wave
    const int c    = lane & 31;       // gram row/col channel
    const int c4   = c >> 2, c3 = c & 3;

    // frag-read ushort indices (kernel-invariant): element (ch=c, px=wv*64+8h+j)
    int jb[8];
#pragma unroll
    for (int j = 0; j < 8; ++j)
        jb[j] = (wv * 64 + 8 * h + j) * 32 + ((c4 ^ j) << 2) + c3;

    floatx16 acc;
#pragma unroll
    for (int i = 0; i < 16; ++i) acc[i] = 0.f;

    for (int tile = blockIdx.x; tile < NTILES; tile += nblk) {
        const int ty = tile / NTILES_X;
        const int tx = tile - ty * NTILES_X;
        const int by = ty * 16, bx = tx * 16;
        const bool interior = (ty >= 1) & (ty <= 62) & (tx >= 1) & (tx <= 62);

        // ---- stage input tile (18x18 per channel) ----
        if (interior) {
            for (int i = t; i < 972; i += 256) {
                int ic  = i / 324;
                int rem = i - ic * 324;
                int r   = rem / 18;
                int cc  = rem - r * 18;
                sIn[i] = x[ic * 1048576 + (by - 2 + r) * 1024 + (bx - 2 + cc)];
            }
        } else {
            for (int i = t; i < 972; i += 256) {
                int ic  = i / 324;
                int rem = i - ic * 324;
                int r   = rem / 18;
                int cc  = rem - r * 18;
                int iy  = by - 2 + r;
                int ix  = bx - 2 + cc;
                float v = 0.f;
                if ((unsigned)iy < 1024u && (unsigned)ix < 1024u)
                    v = x[ic * 1048576 + iy * 1024 + ix];
                sIn[i] = v;
            }
        }
        __syncthreads();

        // ---- conv: 1 px/thread, 32 output channels, write bf16 ----
        {
            const int py = t >> 4, px = t & 15;
            float in[27];
#pragma unroll
            for (int ic = 0; ic < 3; ++ic)
#pragma unroll
                for (int ky = 0; ky < 3; ++ky)
#pragma unroll
                    for (int kx = 0; kx < 3; ++kx)
                        in[ic*9 + ky*3 + kx] = sIn[ic*324 + (py+ky)*18 + (px+kx)];

            const int slotx = t & 7;
            const bool valid = interior || ((by + py) < OHW && (bx + px) < OHW);
            for (int oc4 = 0; oc4 < 8; ++oc4) {
                float a[4];
#pragma unroll
                for (int j = 0; j < 4; ++j) {
                    const int oc = oc4 * 4 + j;
                    float s = b1[oc];
                    const float* wr = w1 + oc * 27;
#pragma unroll
                    for (int k = 0; k < 27; ++k) s = fmaf(in[k], wr[k], s);
                    a[j] = valid ? s : 0.f;
                }
                uint2 w2v = make_uint2(pk2(a[0], a[1]), pk2(a[2], a[3]));
                *(uint2*)&sFb[t * 32 + ((oc4 ^ slotx) << 2)] = w2v;
            }
        }
        __syncthreads();

        // ---- gram: wave wv covers px [wv*64, wv*64+64) in 4 MFMA K-steps ----
#pragma unroll
        for (int s = 0; s < 4; ++s) {
            union { uint u[4]; bf16x8 v; } fu;
#pragma unroll
            for (int q = 0; q < 4; ++q) {
                ushort lo = sFb[jb[2*q]     + s * 512];
                ushort hi = sFb[jb[2*q + 1] + s * 512];
                fu.u[q] = (uint)lo | ((uint)hi << 16);
            }
            acc = __builtin_amdgcn_mfma_f32_32x32x16_bf16(fu.v, fu.v, acc, 0, 0, 0);
        }
        __syncthreads();   // protect sIn/sFb for next iteration
    }

    // ---- epilogue: C-layout scatter to LDS, cross-wave reduce, store ----
    {
        float* gp = (float*)sFb;   // 4 waves x 1024 floats = 16 KB (exact)
#pragma unroll
        for (int r = 0; r < 16; ++r) {
            const int row = (r & 3) + 8 * (r >> 2) + 4 * h;
            gp[wv * 1024 + row * 32 + c] = acc[r];
        }
    }
    __syncthreads();
    {
        float* gp = (float*)sFb;
        const int e = t * 4;
        float s[4] = {0.f, 0.f, 0.f, 0.f};
#pragma unroll
        for (int w = 0; w < 4; ++w) {
            float v[4];
            *(float4*)v = *(const float4*)&gp[w * 1024 + e];
#pragma unroll
            for (int j = 0; j < 4; ++j) s[j] += v[j];
        }
        *(float4*)&partial[(size_t)blockIdx.x * 1024 + e] = *(float4*)s;
    }
}

// ---------------------------------------------------------------------------
// Kernel 2: reduce nblk partials -> NCHUNK partials (coalesced)
// ---------------------------------------------------------------------------
__global__ __launch_bounds__(256) void k_reduce(
    const float* __restrict__ partial, float* __restrict__ partial2, int nblk)
{
    const int gt    = blockIdx.x * 256 + threadIdx.x;  // 0..32767
    const int e     = gt & 1023;
    const int chunk = gt >> 10;                        // 0..31
    float s = 0.f;
    for (int b = chunk; b < nblk; b += NCHUNK) s += partial[(size_t)b * 1024 + e];
    partial2[chunk * 1024 + e] = s;
}

// ---------------------------------------------------------------------------
// Kernel 3: tail — gram finalize + conv2+BN+ReLU + conv3+BN+ReLU + mean
// ---------------------------------------------------------------------------
__global__ __launch_bounds__(1024) void k_tail(
    const float* __restrict__ partial2,
    const float* __restrict__ w2, const float* __restrict__ b2,
    const float* __restrict__ g2, const float* __restrict__ bt2,
    const float* __restrict__ w3, const float* __restrict__ b3,
    const float* __restrict__ g3, const float* __restrict__ bt3,
    float* __restrict__ out)
{
    __shared__ float G[1024];         // 32x32 gram
    __shared__ float y1[16 * 289];    // conv2 out / h1 (17x17)
    __shared__ float y2[32 * 100];    // conv3 out (10x10)
    __shared__ float m1[16], r1[16];
    __shared__ float sw2[144], sp2[48];          // w2; {b2,g2,bt2}
    __shared__ float sw3[4608], sp3[96];         // w3; {b3,g3,bt3}

    const int t = threadIdx.x;

    // ---- stage weights to LDS (coalesced, once) ----
    for (int i = t; i < 144; i += 1024) sw2[i] = w2[i];
    for (int i = t; i < 4608; i += 1024) sw3[i] = w3[i];
    if (t < 16)              sp2[t]      = b2[t];
    else if (t < 32)         sp2[t]      = g2[t - 16];
    else if (t < 48)         sp2[t]      = bt2[t - 32];
    if (t >= 64 && t < 96)   sp3[t - 64] = b3[t - 64];
    else if (t >= 96 && t < 128)  sp3[t - 64] = g3[t - 96];
    else if (t >= 128 && t < 160) sp3[t - 64] = bt3[t - 128];

    // ---- gram finalize: one element per thread ----
    {
        float s = 0.f;
        for (int k = 0; k < NCHUNK; ++k) s += partial2[k * 1024 + t];
        G[t] = s;
    }
    __syncthreads();

    // ---- conv2: 1x32x32 -> 16x17x17, stride 2, pad 2 ----
    for (int idx = t; idx < 16 * 289; idx += 1024) {
        const int oc = idx / 289;
        const int r  = idx - oc * 289;
        const int oy = r / 17, ox = r - (r / 17) * 17;
        float s = sp2[oc];   // b2
#pragma unroll
        for (int ky = 0; ky < 3; ++ky) {
            const int iy = 2 * oy + ky - 2;
            if ((unsigned)iy >= 32u) continue;
#pragma unroll
            for (int kx = 0; kx < 3; ++kx) {
                const int ix = 2 * ox + kx - 2;
                if ((unsigned)ix >= 32u) continue;
                s = fmaf(G[iy * 32 + ix], sw2[oc * 9 + ky * 3 + kx], s);
            }
        }
        y1[idx] = s;
    }
    __syncthreads();

    // ---- BN1 stats: one wave per channel ----
    {
        const int ch = t >> 6, j = t & 63;
        float s = 0.f, ss = 0.f;
        for (int i = j; i < 289; i += 64) {
            float v = y1[ch * 289 + i];
            s += v; ss += v * v;
        }
#pragma unroll
        for (int o = 32; o; o >>= 1) { s += __shfl_xor(s, o); ss += __shfl_xor(ss, o); }
        if (j == 0) {
            float m = s * (1.f / 289.f);
            float var = ss * (1.f / 289.f) - m * m;
            m1[ch] = m;
            r1[ch] = rsqrtf(var + 1e-5f);
        }
    }
    __syncthreads();

    // ---- apply BN1 + ReLU in place ----
    for (int idx = t; idx < 16 * 289; idx += 1024) {
        const int oc = idx / 289;
        float v = (y1[idx] - m1[oc]) * r1[oc] * sp2[16 + oc] + sp2[32 + oc];
        y1[idx] = v > 0.f ? v : 0.f;
    }
    __syncthreads();

    // ---- conv3: 16x17x17 -> 32x10x10, stride 2, pad 2 ----
    for (int idx = t; idx < 3200; idx += 1024) {
        const int oc = idx / 100;
        const int r  = idx - oc * 100;
        const int oy = r / 10, ox = r - (r / 10) * 10;
        float s = sp3[oc];   // b3
        for (int ic = 0; ic < 16; ++ic) {
            const float* yi = y1 + ic * 289;
            const float* wr = sw3 + (oc * 16 + ic) * 9;
#pragma unroll
            for (int ky = 0; ky < 3; ++ky) {
                const int iy = 2 * oy + ky - 2;
                if ((unsigned)iy >= 17u) continue;
#pragma unroll
                for (int kx = 0; kx < 3; ++kx) {
                    const int ix = 2 * ox + kx - 2;
                    if ((unsigned)ix >= 17u) continue;
                    s = fmaf(yi[iy * 17 + ix], wr[ky * 3 + kx], s);
                }
            }
        }
        y2[idx] = s;
    }
    __syncthreads();

    // ---- BN2 + ReLU + spatial mean: 32 lanes per channel ----
    {
        const int ch = t >> 5, j = t & 31;
        float s = 0.f, ss = 0.f;
        for (int i = j; i < 100; i += 32) {
            float v = y2[ch * 100 + i];
            s += v; ss += v * v;
        }
#pragma unroll
        for (int o = 16; o; o >>= 1) { s += __shfl_xor(s, o); ss += __shfl_xor(ss, o); }
        const float m  = s * 0.01f;
        const float var = ss * 0.01f - m * m;
        const float rs = rsqrtf(var + 1e-5f);
        float a = 0.f;
        for (int i = j; i < 100; i += 32) {
            float v = (y2[ch * 100 + i] - m) * rs * sp3[32 + ch] + sp3[64 + ch];
            a += v > 0.f ? v : 0.f;
        }
#pragma unroll
        for (int o = 16; o; o >>= 1) a += __shfl_xor(a, o);
        if (j == 0) out[ch] = a * 0.01f;
    }
}

// ---------------------------------------------------------------------------
extern "C" void kernel_launch(void* const* d_in, const int* in_sizes, int n_in,
                              void* d_out, int out_size, void* d_ws, size_t ws_size,
                              hipStream_t stream)
{
    const float* x   = (const float*)d_in[0];
    const float* w1  = (const float*)d_in[1];
    const float* b1  = (const float*)d_in[2];
    const float* w2  = (const float*)d_in[3];
    const float* b2  = (const float*)d_in[4];
    const float* g2  = (const float*)d_in[5];
    const float* bt2 = (const float*)d_in[6];
    const float* w3  = (const float*)d_in[7];
    const float* b3  = (const float*)d_in[8];
    const float* g3  = (const float*)d_in[9];
    const float* bt3 = (const float*)d_in[10];

    // size grid from workspace: nblk partial grams (4 KB each) + NCHUNK stage-2
    size_t cap = ws_size / 4096;
    int nblk = (cap > (size_t)(NTILES + NCHUNK)) ? NTILES : (int)cap - NCHUNK;
    if (nblk > NTILES) nblk = NTILES;
    if (nblk < 256) nblk = 256;

    float* P   = (float*)d_ws;                 // [nblk][1024]
    float* P2  = P + (size_t)nblk * 1024;      // [NCHUNK][1024]
    float* out = (float*)d_out;                // 32 floats

    k_conv_gram<<<nblk, 256, 0, stream>>>(x, w1, b1, P, nblk);
    k_reduce<<<128, 256, 0, stream>>>(P, P2, nblk);
    k_tail<<<1, 1024, 0, stream>>>(P2, w2, b2, g2, bt2, w3, b3, g3, bt3, out);
}

// Round 5
// 192.139 us; speedup vs baseline: 1.0150x; 1.0150x over previous
//
#include <hip/hip_runtime.h>

#define NTILES_X 65          // ceil(1026/16)
#define NTILES   (65*65)     // 4225
#define OHW      1026
#define NCHUNK   32

typedef unsigned int  uint;
typedef unsigned short ushort;
typedef float  floatx16 __attribute__((ext_vector_type(16)));
typedef __bf16 bf16x8   __attribute__((ext_vector_type(8)));

__device__ __forceinline__ uint pk2(float a, float b) {
    ushort lo = __builtin_bit_cast(ushort, (__bf16)a);
    ushort hi = __builtin_bit_cast(ushort, (__bf16)b);
    return (uint)lo | ((uint)hi << 16);
}

// ---------------------------------------------------------------------------
// Kernel 1: fused conv1 (3->32, k3, pad2, fp32 VALU) + MFMA bf16 gram
// F stored as bf16 [px][32ch], 8B-slot-swizzled: slot(oc4) at (oc4 ^ (px&7)).
// launch_bounds(256,4): 128-VGPR budget so in[27] stays in registers
// (R4's (256,6) -> 40 VGPR -> LDS remat of in[] was a 45% regression).
// ---------------------------------------------------------------------------
__global__ __launch_bounds__(256, 4) void k_conv_gram(
    const float* __restrict__ x,   // [3][1024][1024]
    const float* __restrict__ w1,  // [32][3][3][3]
    const float* __restrict__ b1,  // [32]
    float* __restrict__ partial,   // [nblk][1024]
    int nblk)
{
    __shared__ float  sIn[3*18*18];    // 3.9 KB input tile + halo
    __shared__ ushort sFb[256*32];     // 16 KB bf16 F[px][ch]; aliased for reduce

    const int t    = threadIdx.x;
    const int wv   = t >> 6;
    const int lane = t & 63;
    const int h    = lane >> 5;       // half-wave
    const int c    = lane & 31;       // gram row/col channel
    const int c4   = c >> 2, c3 = c & 3;

    // frag-read ushort indices (kernel-invariant): element (ch=c, px=wv*64+8h+j)
    int jb[8];
#pragma unroll
    for (int j = 0; j < 8; ++j)
        jb[j] = (wv * 64 + 8 * h + j) * 32 + ((c4 ^ j) << 2) + c3;

    floatx16 acc;
#pragma unroll
    for (int i = 0; i < 16; ++i) acc[i] = 0.f;

    for (int tile = blockIdx.x; tile < NTILES; tile += nblk) {
        const int ty = tile / NTILES_X;
        const int tx = tile - ty * NTILES_X;
        const int by = ty * 16, bx = tx * 16;
        const bool interior = (ty >= 1) & (ty <= 62) & (tx >= 1) & (tx <= 62);

        // ---- stage input tile (18x18 per channel) ----
        if (interior) {
            for (int i = t; i < 972; i += 256) {
                int ic  = i / 324;
                int rem = i - ic * 324;
                int r   = rem / 18;
                int cc  = rem - r * 18;
                sIn[i] = x[ic * 1048576 + (by - 2 + r) * 1024 + (bx - 2 + cc)];
            }
        } else {
            for (int i = t; i < 972; i += 256) {
                int ic  = i / 324;
                int rem = i - ic * 324;
                int r   = rem / 18;
                int cc  = rem - r * 18;
                int iy  = by - 2 + r;
                int ix  = bx - 2 + cc;
                float v = 0.f;
                if ((unsigned)iy < 1024u && (unsigned)ix < 1024u)
                    v = x[ic * 1048576 + iy * 1024 + ix];
                sIn[i] = v;
            }
        }
        __syncthreads();

        // ---- conv: 1 px/thread, 32 output channels, write bf16 ----
        {
            const int py = t >> 4, px = t & 15;
            float in[27];
#pragma unroll
            for (int ic = 0; ic < 3; ++ic)
#pragma unroll
                for (int ky = 0; ky < 3; ++ky)
#pragma unroll
                    for (int kx = 0; kx < 3; ++kx)
                        in[ic*9 + ky*3 + kx] = sIn[ic*324 + (py+ky)*18 + (px+kx)];

            const int slotx = t & 7;
            const bool valid = interior || ((by + py) < OHW && (bx + px) < OHW);
            for (int oc4 = 0; oc4 < 8; ++oc4) {
                float a[4];
#pragma unroll
                for (int j = 0; j < 4; ++j) {
                    const int oc = oc4 * 4 + j;
                    float s = b1[oc];
                    const float* wr = w1 + oc * 27;
#pragma unroll
                    for (int k = 0; k < 27; ++k) s = fmaf(in[k], wr[k], s);
                    a[j] = valid ? s : 0.f;
                }
                uint2 w2v = make_uint2(pk2(a[0], a[1]), pk2(a[2], a[3]));
                *(uint2*)&sFb[t * 32 + ((oc4 ^ slotx) << 2)] = w2v;
            }
        }
        __syncthreads();

        // ---- gram: wave wv covers px [wv*64, wv*64+64) in 4 MFMA K-steps ----
#pragma unroll
        for (int s = 0; s < 4; ++s) {
            union { uint u[4]; bf16x8 v; } fu;
#pragma unroll
            for (int q = 0; q < 4; ++q) {
                ushort lo = sFb[jb[2*q]     + s * 512];
                ushort hi = sFb[jb[2*q + 1] + s * 512];
                fu.u[q] = (uint)lo | ((uint)hi << 16);
            }
            acc = __builtin_amdgcn_mfma_f32_32x32x16_bf16(fu.v, fu.v, acc, 0, 0, 0);
        }
        __syncthreads();   // protect sIn/sFb for next iteration
    }

    // ---- epilogue: C-layout scatter to LDS, cross-wave reduce, store ----
    {
        float* gp = (float*)sFb;   // 4 waves x 1024 floats = 16 KB (exact)
#pragma unroll
        for (int r = 0; r < 16; ++r) {
            const int row = (r & 3) + 8 * (r >> 2) + 4 * h;
            gp[wv * 1024 + row * 32 + c] = acc[r];
        }
    }
    __syncthreads();
    {
        float* gp = (float*)sFb;
        const int e = t * 4;
        float s[4] = {0.f, 0.f, 0.f, 0.f};
#pragma unroll
        for (int w = 0; w < 4; ++w) {
            float v[4];
            *(float4*)v = *(const float4*)&gp[w * 1024 + e];
#pragma unroll
            for (int j = 0; j < 4; ++j) s[j] += v[j];
        }
        *(float4*)&partial[(size_t)blockIdx.x * 1024 + e] = *(float4*)s;
    }
}

// ---------------------------------------------------------------------------
// Kernel 2: reduce nblk partials -> NCHUNK partials (coalesced)
// ---------------------------------------------------------------------------
__global__ __launch_bounds__(256) void k_reduce(
    const float* __restrict__ partial, float* __restrict__ partial2, int nblk)
{
    const int gt    = blockIdx.x * 256 + threadIdx.x;  // 0..32767
    const int e     = gt & 1023;
    const int chunk = gt >> 10;                        // 0..31
    float s = 0.f;
    for (int b = chunk; b < nblk; b += NCHUNK) s += partial[(size_t)b * 1024 + e];
    partial2[chunk * 1024 + e] = s;
}

// ---------------------------------------------------------------------------
// Kernel 3: tail — gram finalize + conv2+BN+ReLU + conv3+BN+ReLU + mean
// ---------------------------------------------------------------------------
__global__ __launch_bounds__(1024) void k_tail(
    const float* __restrict__ partial2,
    const float* __restrict__ w2, const float* __restrict__ b2,
    const float* __restrict__ g2, const float* __restrict__ bt2,
    const float* __restrict__ w3, const float* __restrict__ b3,
    const float* __restrict__ g3, const float* __restrict__ bt3,
    float* __restrict__ out)
{
    __shared__ float G[1024];         // 32x32 gram
    __shared__ float y1[16 * 289];    // conv2 out / h1 (17x17)
    __shared__ float y2[32 * 100];    // conv3 out (10x10)
    __shared__ float m1[16], r1[16];
    __shared__ float sw2[144], sp2[48];          // w2; {b2,g2,bt2}
    __shared__ float sw3[4608], sp3[96];         // w3; {b3,g3,bt3}

    const int t = threadIdx.x;

    // ---- stage weights to LDS (coalesced, once) ----
    for (int i = t; i < 144; i += 1024) sw2[i] = w2[i];
    for (int i = t; i < 4608; i += 1024) sw3[i] = w3[i];
    if (t < 16)              sp2[t]      = b2[t];
    else if (t < 32)         sp2[t]      = g2[t - 16];
    else if (t < 48)         sp2[t]      = bt2[t - 32];
    if (t >= 64 && t < 96)   sp3[t - 64] = b3[t - 64];
    else if (t >= 96 && t < 128)  sp3[t - 64] = g3[t - 96];
    else if (t >= 128 && t < 160) sp3[t - 64] = bt3[t - 128];

    // ---- gram finalize: one element per thread ----
    {
        float s = 0.f;
        for (int k = 0; k < NCHUNK; ++k) s += partial2[k * 1024 + t];
        G[t] = s;
    }
    __syncthreads();

    // ---- conv2: 1x32x32 -> 16x17x17, stride 2, pad 2 ----
    for (int idx = t; idx < 16 * 289; idx += 1024) {
        const int oc = idx / 289;
        const int r  = idx - oc * 289;
        const int oy = r / 17, ox = r - (r / 17) * 17;
        float s = sp2[oc];   // b2
#pragma unroll
        for (int ky = 0; ky < 3; ++ky) {
            const int iy = 2 * oy + ky - 2;
            if ((unsigned)iy >= 32u) continue;
#pragma unroll
            for (int kx = 0; kx < 3; ++kx) {
                const int ix = 2 * ox + kx - 2;
                if ((unsigned)ix >= 32u) continue;
                s = fmaf(G[iy * 32 + ix], sw2[oc * 9 + ky * 3 + kx], s);
            }
        }
        y1[idx] = s;
    }
    __syncthreads();

    // ---- BN1 stats: one wave per channel ----
    {
        const int ch = t >> 6, j = t & 63;
        float s = 0.f, ss = 0.f;
        for (int i = j; i < 289; i += 64) {
            float v = y1[ch * 289 + i];
            s += v; ss += v * v;
        }
#pragma unroll
        for (int o = 32; o; o >>= 1) { s += __shfl_xor(s, o); ss += __shfl_xor(ss, o); }
        if (j == 0) {
            float m = s * (1.f / 289.f);
            float var = ss * (1.f / 289.f) - m * m;
            m1[ch] = m;
            r1[ch] = rsqrtf(var + 1e-5f);
        }
    }
    __syncthreads();

    // ---- apply BN1 + ReLU in place ----
    for (int idx = t; idx < 16 * 289; idx += 1024) {
        const int oc = idx / 289;
        float v = (y1[idx] - m1[oc]) * r1[oc] * sp2[16 + oc] + sp2[32 + oc];
        y1[idx] = v > 0.f ? v : 0.f;
    }
    __syncthreads();

    // ---- conv3: 16x17x17 -> 32x10x10, stride 2, pad 2 ----
    for (int idx = t; idx < 3200; idx += 1024) {
        const int oc = idx / 100;
        const int r  = idx - oc * 100;
        const int oy = r / 10, ox = r - (r / 10) * 10;
        float s = sp3[oc];   // b3
        for (int ic = 0; ic < 16; ++ic) {
            const float* yi = y1 + ic * 289;
            const float* wr = sw3 + (oc * 16 + ic) * 9;
#pragma unroll
            for (int ky = 0; ky < 3; ++ky) {
                const int iy = 2 * oy + ky - 2;
                if ((unsigned)iy >= 17u) continue;
#pragma unroll
                for (int kx = 0; kx < 3; ++kx) {
                    const int ix = 2 * ox + kx - 2;
                    if ((unsigned)ix >= 17u) continue;
                    s = fmaf(yi[iy * 17 + ix], wr[ky * 3 + kx], s);
                }
            }
        }
        y2[idx] = s;
    }
    __syncthreads();

    // ---- BN2 + ReLU + spatial mean: 32 lanes per channel ----
    {
        const int ch = t >> 5, j = t & 31;
        float s = 0.f, ss = 0.f;
        for (int i = j; i < 100; i += 32) {
            float v = y2[ch * 100 + i];
            s += v; ss += v * v;
        }
#pragma unroll
        for (int o = 16; o; o >>= 1) { s += __shfl_xor(s, o); ss += __shfl_xor(ss, o); }
        const float m  = s * 0.01f;
        const float var = ss * 0.01f - m * m;
        const float rs = rsqrtf(var + 1e-5f);
        float a = 0.f;
        for (int i = j; i < 100; i += 32) {
            float v = (y2[ch * 100 + i] - m) * rs * sp3[32 + ch] + sp3[64 + ch];
            a += v > 0.f ? v : 0.f;
        }
#pragma unroll
        for (int o = 16; o; o >>= 1) a += __shfl_xor(a, o);
        if (j == 0) out[ch] = a * 0.01f;
    }
}

// ---------------------------------------------------------------------------
extern "C" void kernel_launch(void* const* d_in, const int* in_sizes, int n_in,
                              void* d_out, int out_size, void* d_ws, size_t ws_size,
                              hipStream_t stream)
{
    const float* x   = (const float*)d_in[0];
    const float* w1  = (const float*)d_in[1];
    const float* b1  = (const float*)d_in[2];
    const float* w2  = (const float*)d_in[3];
    const float* b2  = (const float*)d_in[4];
    const float* g2  = (const float*)d_in[5];
    const float* bt2 = (const float*)d_in[6];
    const float* w3  = (const float*)d_in[7];
    const float* b3  = (const float*)d_in[8];
    const float* g3  = (const float*)d_in[9];
    const float* bt3 = (const float*)d_in[10];

    // size grid from workspace: nblk partial grams (4 KB each) + NCHUNK stage-2
    size_t cap = ws_size / 4096;
    int nblk = (cap > (size_t)(NTILES + NCHUNK)) ? NTILES : (int)cap - NCHUNK;
    if (nblk > NTILES) nblk = NTILES;
    if (nblk < 256) nblk = 256;

    float* P   = (float*)d_ws;                 // [nblk][1024]
    float* P2  = P + (size_t)nblk * 1024;      // [NCHUNK][1024]
    float* out = (float*)d_out;                // 32 floats

    k_conv_gram<<<nblk, 256, 0, stream>>>(x, w1, b1, P, nblk);
    k_reduce<<<128, 256, 0, stream>>>(P, P2, nblk);
    k_tail<<<1, 1024, 0, stream>>>(P2, w2, b2, g2, bt2, g3 ? w3 : w3, b3, g3, bt3, out);
}

// Round 6
// 103.686 us; speedup vs baseline: 1.8809x; 1.8531x over previous
//
#include <hip/hip_runtime.h>

#define NTILES_X 65          // ceil(1026/16)
#define NTILES   (65*65)     // 4225
#define OHW      1026
#define NCHUNK   32

typedef unsigned int  uint;
typedef unsigned short ushort;
typedef float  floatx16 __attribute__((ext_vector_type(16)));
typedef __bf16 bf16x8   __attribute__((ext_vector_type(8)));

__device__ __forceinline__ uint pk2f(float a, float b) {
    ushort lo = __builtin_bit_cast(ushort, (__bf16)a);
    ushort hi = __builtin_bit_cast(ushort, (__bf16)b);
    return (uint)lo | ((uint)hi << 16);
}
__device__ __forceinline__ bf16x8 frag_of(uint a, uint b, uint c, uint d) {
    uint4 u = make_uint4(a, b, c, d);
    return __builtin_bit_cast(bf16x8, u);
}
// k -> element offset in sInB[3][18][18]  (k = ic*9 + ky*3 + kx)
__device__ __forceinline__ constexpr int koff_of(int k) {
    return (k / 9) * 324 + ((k % 9) / 3) * 18 + (k % 3);
}
// one B-frag u16: slot k = (h ? kb : ka); ka,kb compile-time (kb = ka+8).
// k==27 is the bias slot (B=1.0); k>27 -> 0.
__device__ __forceinline__ uint bslot(const ushort* sInB, int base, int h, int ka, int kb) {
    if (kb < 27) {
        int off = h ? koff_of(kb) : koff_of(ka);
        return (uint)sInB[base + off];
    } else if (ka < 27) {
        uint cst = (kb == 27) ? 0x3F80u : 0u;
        uint rd  = (uint)sInB[base + koff_of(ka)];
        return h ? cst : rd;
    } else {
        uint ca = (ka == 27) ? 0x3F80u : 0u;
        uint cb = (kb == 27) ? 0x3F80u : 0u;
        return h ? cb : ca;
    }
}

// ---------------------------------------------------------------------------
// Kernel 1: conv1 (3->32, k3, pad2) via implicit-GEMM MFMA + MFMA bf16 gram.
// κ(s,h,j) = s*16 + h*8 + j for BOTH W and patch frags (consistency is all
// that correctness needs; Σ_k is permutation-invariant). Bias folded in k=27.
// F stored bf16 [px][32ch], slot-swizzled (slot ^ (px&7)) as in R5 (proven).
// ---------------------------------------------------------------------------
__global__ __launch_bounds__(256, 4) void k_conv_gram(
    const float* __restrict__ x,   // [3][1024][1024]
    const float* __restrict__ w1,  // [32][3][3][3]
    const float* __restrict__ b1,  // [32]
    float* __restrict__ partial,   // [nblk][1024]
    int nblk)
{
    __shared__ __align__(16) ushort sInB[3*18*18];   // 1.9 KB bf16 input tile
    __shared__ __align__(16) ushort sFb[256*32];     // 16 KB bf16 F; aliased for reduce

    const int t    = threadIdx.x;
    const int wv   = t >> 6;
    const int lane = t & 63;
    const int h    = lane >> 5;
    const int c    = lane & 31;        // oc for W-frag / ch for gram / px-col for B-frag
    const int c4   = c >> 2, c3 = c & 3;

    // ---- weight(+bias) fragments, built once ----
    const float b1c = b1[c];
    uint wu0[4], wu1[4];
#pragma unroll
    for (int q = 0; q < 4; ++q) {
        {   // s=0: k = h*8 + 2q, +1  (all < 16, real)
            int k0 = h * 8 + 2 * q;
            wu0[q] = pk2f(w1[c * 27 + k0], w1[c * 27 + k0 + 1]);
        }
        {   // s=1: k = 16 + h*8 + 2q, +1  (27 -> bias, >27 -> 0)
            int k0 = 16 + h * 8 + 2 * q, k1 = k0 + 1;
            float r0 = w1[c * 27 + (k0 < 27 ? k0 : 26)];
            float r1 = w1[c * 27 + (k1 < 27 ? k1 : 26)];
            float v0 = (k0 < 27) ? r0 : (k0 == 27 ? b1c : 0.f);
            float v1 = (k1 < 27) ? r1 : (k1 == 27 ? b1c : 0.f);
            wu1[q] = pk2f(v0, v1);
        }
    }

    floatx16 gacc;
#pragma unroll
    for (int i = 0; i < 16; ++i) gacc[i] = 0.f;

    for (int tile = blockIdx.x; tile < NTILES; tile += nblk) {
        const int ty = tile / NTILES_X;
        const int tx = tile - ty * NTILES_X;
        const int by = ty * 16, bx = tx * 16;
        const bool interior = (ty >= 1) & (ty <= 62) & (tx >= 1) & (tx <= 62);

        __syncthreads();   // prev-tile conv reads of sInB are done
        // ---- stage input tile as bf16 ----
        if (interior) {
            for (int i = t; i < 972; i += 256) {
                int ic = i / 324, rem = i - ic * 324, r = rem / 18, cc = rem - r * 18;
                float v = x[ic * 1048576 + (by - 2 + r) * 1024 + (bx - 2 + cc)];
                sInB[i] = __builtin_bit_cast(ushort, (__bf16)v);
            }
        } else {
            for (int i = t; i < 972; i += 256) {
                int ic = i / 324, rem = i - ic * 324, r = rem / 18, cc = rem - r * 18;
                int iy = by - 2 + r, ix = bx - 2 + cc;
                float v = 0.f;
                if ((unsigned)iy < 1024u && (unsigned)ix < 1024u)
                    v = x[ic * 1048576 + iy * 1024 + ix];
                sInB[i] = __builtin_bit_cast(ushort, (__bf16)v);
            }
        }
        __syncthreads();   // sInB ready

        // ---- conv: wave wv owns col-blocks 2wv, 2wv+1 (64 px) ----
#pragma unroll
        for (int e = 0; e < 2; ++e) {
            const int cb   = 2 * wv + e;
            const int px   = cb * 32 + c;
            const int base = (cb * 2 + (c >> 4)) * 18 + (c & 15);

            floatx16 cacc;
#pragma unroll
            for (int i = 0; i < 16; ++i) cacc[i] = 0.f;

            uint bu[4];
#pragma unroll
            for (int q = 0; q < 4; ++q) {
                uint lo = bslot(sInB, base, h, 2*q,     2*q + 8);
                uint hi = bslot(sInB, base, h, 2*q + 1, 2*q + 9);
                bu[q] = lo | (hi << 16);
            }
            cacc = __builtin_amdgcn_mfma_f32_32x32x16_bf16(
                frag_of(wu0[0], wu0[1], wu0[2], wu0[3]),
                frag_of(bu[0], bu[1], bu[2], bu[3]), cacc, 0, 0, 0);
#pragma unroll
            for (int q = 0; q < 4; ++q) {
                uint lo = bslot(sInB, base, h, 16 + 2*q,     16 + 2*q + 8);
                uint hi = bslot(sInB, base, h, 16 + 2*q + 1, 16 + 2*q + 9);
                bu[q] = lo | (hi << 16);
            }
            cacc = __builtin_amdgcn_mfma_f32_32x32x16_bf16(
                frag_of(wu1[0], wu1[1], wu1[2], wu1[3]),
                frag_of(bu[0], bu[1], bu[2], bu[3]), cacc, 0, 0, 0);

            // ---- F write: rows(reg 4q+m) = 8q+4h+m ; mask invalid px ----
            const int py = px >> 4, pxx = px & 15;
            const uint vmask = ((by + py) < OHW && (bx + pxx) < OHW) ? 0xFFFFFFFFu : 0u;
#pragma unroll
            for (int q = 0; q < 4; ++q) {
                uint u0 = pk2f(cacc[4*q + 0], cacc[4*q + 1]) & vmask;
                uint u1 = pk2f(cacc[4*q + 2], cacc[4*q + 3]) & vmask;
                *(uint2*)&sFb[px * 32 + (((2*q + h) ^ (px & 7)) << 2)] = make_uint2(u0, u1);
            }
        }

        // ---- gram: own 64-px range, 4 K-steps (reads only own wave's writes) ----
#pragma unroll
        for (int s4 = 0; s4 < 4; ++s4) {
            const int pxg = wv * 64 + 16 * s4 + 8 * h;
            uint gu[4];
#pragma unroll
            for (int q = 0; q < 4; ++q) {
                const int j0 = 2 * q, j1 = 2 * q + 1;
                uint lo = sFb[(pxg + j0) * 32 + ((c4 ^ j0) << 2) + c3];
                uint hi = sFb[(pxg + j1) * 32 + ((c4 ^ j1) << 2) + c3];
                gu[q] = lo | (hi << 16);
            }
            bf16x8 gf = frag_of(gu[0], gu[1], gu[2], gu[3]);
            gacc = __builtin_amdgcn_mfma_f32_32x32x16_bf16(gf, gf, gacc, 0, 0, 0);
        }
    }

    // ---- epilogue: C-layout scatter, cross-wave reduce, store ----
    __syncthreads();
    {
        float* gp = (float*)sFb;   // 4 waves x 1024 f32 = 16 KB (exact)
#pragma unroll
        for (int r = 0; r < 16; ++r) {
            const int row = (r & 3) + 8 * (r >> 2) + 4 * h;
            gp[wv * 1024 + row * 32 + c] = gacc[r];
        }
    }
    __syncthreads();
    {
        float* gp = (float*)sFb;
        const int e = t * 4;
        float s[4] = {0.f, 0.f, 0.f, 0.f};
#pragma unroll
        for (int w = 0; w < 4; ++w) {
            float v[4];
            *(float4*)v = *(const float4*)&gp[w * 1024 + e];
#pragma unroll
            for (int j = 0; j < 4; ++j) s[j] += v[j];
        }
        *(float4*)&partial[(size_t)blockIdx.x * 1024 + e] = *(float4*)s;
    }
}

// ---------------------------------------------------------------------------
// Kernel 2: reduce nblk partials -> NCHUNK partials (coalesced)
// ---------------------------------------------------------------------------
__global__ __launch_bounds__(256) void k_reduce(
    const float* __restrict__ partial, float* __restrict__ partial2, int nblk)
{
    const int gt    = blockIdx.x * 256 + threadIdx.x;
    const int e     = gt & 1023;
    const int chunk = gt >> 10;
    float s = 0.f;
    for (int b = chunk; b < nblk; b += NCHUNK) s += partial[(size_t)b * 1024 + e];
    partial2[chunk * 1024 + e] = s;
}

// ---------------------------------------------------------------------------
// Kernel 3: tail — gram finalize + conv2+BN+ReLU + conv3+BN+ReLU + mean
// ---------------------------------------------------------------------------
__global__ __launch_bounds__(1024) void k_tail(
    const float* __restrict__ partial2,
    const float* __restrict__ w2, const float* __restrict__ b2,
    const float* __restrict__ g2, const float* __restrict__ bt2,
    const float* __restrict__ w3, const float* __restrict__ b3,
    const float* __restrict__ g3, const float* __restrict__ bt3,
    float* __restrict__ out)
{
    __shared__ float G[1024];
    __shared__ float y1[16 * 289];
    __shared__ float y2[32 * 100];
    __shared__ float m1[16], r1[16];
    __shared__ float sw2[144], sp2[48];
    __shared__ float sw3[4608], sp3[96];

    const int t = threadIdx.x;

    for (int i = t; i < 144; i += 1024) sw2[i] = w2[i];
    for (int i = t; i < 4608; i += 1024) sw3[i] = w3[i];
    if (t < 16)              sp2[t]      = b2[t];
    else if (t < 32)         sp2[t]      = g2[t - 16];
    else if (t < 48)         sp2[t]      = bt2[t - 32];
    if (t >= 64 && t < 96)   sp3[t - 64] = b3[t - 64];
    else if (t >= 96 && t < 128)  sp3[t - 64] = g3[t - 96];
    else if (t >= 128 && t < 160) sp3[t - 64] = bt3[t - 128];

    {
        float s = 0.f;
        for (int k = 0; k < NCHUNK; ++k) s += partial2[k * 1024 + t];
        G[t] = s;
    }
    __syncthreads();

    for (int idx = t; idx < 16 * 289; idx += 1024) {
        const int oc = idx / 289;
        const int r  = idx - oc * 289;
        const int oy = r / 17, ox = r - (r / 17) * 17;
        float s = sp2[oc];
#pragma unroll
        for (int ky = 0; ky < 3; ++ky) {
            const int iy = 2 * oy + ky - 2;
            if ((unsigned)iy >= 32u) continue;
#pragma unroll
            for (int kx = 0; kx < 3; ++kx) {
                const int ix = 2 * ox + kx - 2;
                if ((unsigned)ix >= 32u) continue;
                s = fmaf(G[iy * 32 + ix], sw2[oc * 9 + ky * 3 + kx], s);
            }
        }
        y1[idx] = s;
    }
    __syncthreads();

    {
        const int ch = t >> 6, j = t & 63;
        float s = 0.f, ss = 0.f;
        for (int i = j; i < 289; i += 64) {
            float v = y1[ch * 289 + i];
            s += v; ss += v * v;
        }
#pragma unroll
        for (int o = 32; o; o >>= 1) { s += __shfl_xor(s, o); ss += __shfl_xor(ss, o); }
        if (j == 0) {
            float m = s * (1.f / 289.f);
            float var = ss * (1.f / 289.f) - m * m;
            m1[ch] = m;
            r1[ch] = rsqrtf(var + 1e-5f);
        }
    }
    __syncthreads();

    for (int idx = t; idx < 16 * 289; idx += 1024) {
        const int oc = idx / 289;
        float v = (y1[idx] - m1[oc]) * r1[oc] * sp2[16 + oc] + sp2[32 + oc];
        y1[idx] = v > 0.f ? v : 0.f;
    }
    __syncthreads();

    for (int idx = t; idx < 3200; idx += 1024) {
        const int oc = idx / 100;
        const int r  = idx - oc * 100;
        const int oy = r / 10, ox = r - (r / 10) * 10;
        float s = sp3[oc];
        for (int ic = 0; ic < 16; ++ic) {
            const float* yi = y1 + ic * 289;
            const float* wr = sw3 + (oc * 16 + ic) * 9;
#pragma unroll
            for (int ky = 0; ky < 3; ++ky) {
                const int iy = 2 * oy + ky - 2;
                if ((unsigned)iy >= 17u) continue;
#pragma unroll
                for (int kx = 0; kx < 3; ++kx) {
                    const int ix = 2 * ox + kx - 2;
                    if ((unsigned)ix >= 17u) continue;
                    s = fmaf(yi[iy * 17 + ix], wr[ky * 3 + kx], s);
                }
            }
        }
        y2[idx] = s;
    }
    __syncthreads();

    {
        const int ch = t >> 5, j = t & 31;
        float s = 0.f, ss = 0.f;
        for (int i = j; i < 100; i += 32) {
            float v = y2[ch * 100 + i];
            s += v; ss += v * v;
        }
#pragma unroll
        for (int o = 16; o; o >>= 1) { s += __shfl_xor(s, o); ss += __shfl_xor(ss, o); }
        const float m  = s * 0.01f;
        const float var = ss * 0.01f - m * m;
        const float rs = rsqrtf(var + 1e-5f);
        float a = 0.f;
        for (int i = j; i < 100; i += 32) {
            float v = (y2[ch * 100 + i] - m) * rs * sp3[32 + ch] + sp3[64 + ch];
            a += v > 0.f ? v : 0.f;
        }
#pragma unroll
        for (int o = 16; o; o >>= 1) a += __shfl_xor(a, o);
        if (j == 0) out[ch] = a * 0.01f;
    }
}

// ---------------------------------------------------------------------------
extern "C" void kernel_launch(void* const* d_in, const int* in_sizes, int n_in,
                              void* d_out, int out_size, void* d_ws, size_t ws_size,
                              hipStream_t stream)
{
    const float* x   = (const float*)d_in[0];
    const float* w1  = (const float*)d_in[1];
    const float* b1  = (const float*)d_in[2];
    const float* w2  = (const float*)d_in[3];
    const float* b2  = (const float*)d_in[4];
    const float* g2  = (const float*)d_in[5];
    const float* bt2 = (const float*)d_in[6];
    const float* w3  = (const float*)d_in[7];
    const float* b3  = (const float*)d_in[8];
    const float* g3  = (const float*)d_in[9];
    const float* bt3 = (const float*)d_in[10];

    size_t cap = ws_size / 4096;
    int nblk = (cap > (size_t)(NTILES + NCHUNK)) ? NTILES : (int)cap - NCHUNK;
    if (nblk > NTILES) nblk = NTILES;
    if (nblk < 256) nblk = 256;

    float* P   = (float*)d_ws;
    float* P2  = P + (size_t)nblk * 1024;
    float* out = (float*)d_out;

    k_conv_gram<<<nblk, 256, 0, stream>>>(x, w1, b1, P, nblk);
    k_reduce<<<128, 256, 0, stream>>>(P, P2, nblk);
    k_tail<<<1, 1024, 0, stream>>>(P2, w2, b2, g2, bt2, w3, b3, g3, bt3, out);
}